// Round 1
// baseline (464.190 us; speedup 1.0000x reference)
//
#include <hip/hip_runtime.h>
#include <math.h>

#define B_    16
#define CONDC 256
#define ICn   64
#define OCn   64
#define Kn    3
#define Hn    128
#define Wn    128
#define NW    (Kn*Kn*ICn*OCn)        // 36864
#define NPARAM (NW + OCn)            // 36928

// Kernel 1: wb[b][p] = tanh(cond[b]·W_cond[p] + b_cond[p]) * 5
// Block: 256 threads = 16 params x 16 batches. W_cond read exactly once.
__global__ __launch_bounds__(256) void cond_gemm(const float* __restrict__ cond,
                                                 const float* __restrict__ Wc,
                                                 const float* __restrict__ bc,
                                                 float* __restrict__ wb) {
    __shared__ float condl[B_][CONDC + 1];   // +1 pad: break stride-256 bank conflict
    __shared__ float Wl[16][CONDC + 1];
    const int tid = threadIdx.x;
    const int p0 = blockIdx.x * 16;

    for (int i = tid; i < B_ * CONDC; i += 256) {
        int b = i >> 8, k = i & 255;
        condl[b][k] = cond[b * CONDC + k];
    }
    for (int i = tid; i < 16 * CONDC; i += 256) {
        int pl = i >> 8, k = i & 255;
        Wl[pl][k] = Wc[(p0 + pl) * CONDC + k];
    }
    __syncthreads();

    const int pl = tid >> 4;
    const int b  = tid & 15;
    float acc = bc[p0 + pl];
    #pragma unroll 8
    for (int k = 0; k < CONDC; ++k)
        acc += Wl[pl][k] * condl[b][k];
    wb[b * NPARAM + p0 + pl] = tanhf(acc) * 5.0f;
}

// Kernel 2: direct conv, per-batch weights.
// Block: 256 threads; tile = 32x32 spatial x 8 oc; thread = 2x2 pixels x 8 oc.
#define TS  32
#define OG  8
#define ICC 8

__global__ __launch_bounds__(256) void conv_kernel(const float* __restrict__ x,
                                                   const float* __restrict__ wb,
                                                   float* __restrict__ out) {
    __shared__ float xs[ICC][TS + 2][TS + 2];  // 8*34*34*4 = 36992 B
    __shared__ float ws[OG][ICC][9];           // 2304 B

    const int tid = threadIdx.x;
    const int b   = blockIdx.z;
    const int ocg = blockIdx.y * OG;
    const int tx0 = (blockIdx.x & 3) * TS;
    const int ty0 = (blockIdx.x >> 2) * TS;
    const int px  = (tid & 15) * 2;
    const int py  = (tid >> 4) * 2;

    float acc[OG][4];
    #pragma unroll
    for (int o = 0; o < OG; ++o)
        #pragma unroll
        for (int q = 0; q < 4; ++q) acc[o][q] = 0.0f;

    const float* wbase = wb + b * NPARAM;

    for (int ic0 = 0; ic0 < ICn; ic0 += ICC) {
        // ---- stage x tile (with halo, zero-padded) ----
        for (int i = tid; i < ICC * (TS + 2) * (TS + 2); i += 256) {
            int icl = i / ((TS + 2) * (TS + 2));
            int rem = i % ((TS + 2) * (TS + 2));
            int yy = rem / (TS + 2), xx = rem % (TS + 2);
            int gy = ty0 - 1 + yy, gx = tx0 - 1 + xx;
            float v = 0.0f;
            if (gy >= 0 && gy < Hn && gx >= 0 && gx < Wn)
                v = x[((b * ICn + ic0 + icl) * Hn + gy) * Wn + gx];
            xs[icl][yy][xx] = v;
        }
        // ---- stage weights ----
        for (int i = tid; i < OG * ICC * 9; i += 256) {
            int o   = i / (ICC * 9);
            int rem = i % (ICC * 9);
            int icl = rem / 9, k = rem % 9;
            ws[o][icl][k] = wbase[((ocg + o) * ICn + ic0 + icl) * 9 + k];
        }
        __syncthreads();

        #pragma unroll
        for (int icl = 0; icl < ICC; ++icl) {
            float xv[4][4];
            #pragma unroll
            for (int dy = 0; dy < 4; ++dy)
                #pragma unroll
                for (int dx = 0; dx < 4; ++dx)
                    xv[dy][dx] = xs[icl][py + dy][px + dx];
            #pragma unroll
            for (int o = 0; o < OG; ++o) {
                #pragma unroll
                for (int kh = 0; kh < 3; ++kh)
                    #pragma unroll
                    for (int kw = 0; kw < 3; ++kw) {
                        float wv = ws[o][icl][kh * 3 + kw];
                        acc[o][0] += xv[kh    ][kw    ] * wv;
                        acc[o][1] += xv[kh    ][kw + 1] * wv;
                        acc[o][2] += xv[kh + 1][kw    ] * wv;
                        acc[o][3] += xv[kh + 1][kw + 1] * wv;
                    }
            }
        }
        __syncthreads();
    }

    // ---- epilogue: bias + store ----
    #pragma unroll
    for (int o = 0; o < OG; ++o) {
        float bias = wbase[NW + ocg + o];
        int oc = ocg + o;
        float* obase = out + ((size_t)(b * OCn + oc) * Hn + (ty0 + py)) * Wn + tx0 + px;
        obase[0]      = acc[o][0] + bias;
        obase[1]      = acc[o][1] + bias;
        obase[Wn]     = acc[o][2] + bias;
        obase[Wn + 1] = acc[o][3] + bias;
    }
}

extern "C" void kernel_launch(void* const* d_in, const int* in_sizes, int n_in,
                              void* d_out, int out_size, void* d_ws, size_t ws_size,
                              hipStream_t stream) {
    const float* x    = (const float*)d_in[0];
    const float* cond = (const float*)d_in[1];
    const float* Wc   = (const float*)d_in[2];
    const float* bc   = (const float*)d_in[3];
    float* out  = (float*)d_out;
    float* wbuf = (float*)d_ws;   // B*NPARAM floats = 2.36 MB

    cond_gemm<<<dim3(NPARAM / 16), 256, 0, stream>>>(cond, Wc, bc, wbuf);
    conv_kernel<<<dim3(16, OCn / OG, B_), 256, 0, stream>>>(x, wbuf, out);
}

// Round 2
// 116.691 us; speedup vs baseline: 3.9779x; 3.9779x over previous
//
#include <hip/hip_runtime.h>
#include <math.h>
#include <stdint.h>

#define B_    16
#define CONDC 256
#define ICn   64
#define OCn   64
#define Hn    128
#define Wn    128
#define NW    36864
#define NPARAM 36928

typedef _Float16 half8 __attribute__((ext_vector_type(8)));
typedef float f32x4 __attribute__((ext_vector_type(4)));

// ============================ FAST PATH ============================

// K1: params -> wt f16 [b][tap][oc][ic] + bias f32 [b][oc]
__global__ __launch_bounds__(256) void cond_gemm_f16(const float* __restrict__ cond,
                                                     const float* __restrict__ Wc,
                                                     const float* __restrict__ bc,
                                                     _Float16* __restrict__ wt,
                                                     float* __restrict__ bias) {
    __shared__ float condl[B_][CONDC + 1];
    __shared__ float Wl[16][CONDC + 1];
    const int tid = threadIdx.x;
    const int p0 = blockIdx.x * 16;
    for (int i = tid; i < B_ * CONDC; i += 256) condl[i >> 8][i & 255] = cond[i];
    for (int i = tid; i < 16 * CONDC; i += 256) {
        int pl = i >> 8, k = i & 255;
        Wl[pl][k] = Wc[(p0 + pl) * CONDC + k];
    }
    __syncthreads();
    const int pl = tid >> 4;
    const int b  = tid & 15;
    float acc = bc[p0 + pl];
    #pragma unroll 8
    for (int k = 0; k < CONDC; ++k) acc += Wl[pl][k] * condl[b][k];
    float val = tanhf(acc) * 5.0f;
    int p = p0 + pl;
    if (p < NW) {
        int oc = p / 576, rem = p % 576;
        int ic = rem / 9,  t  = rem % 9;
        wt[(((size_t)b * 9 + t) * 64 + oc) * 64 + ic] = (_Float16)val;
    } else {
        bias[b * 64 + (p - NW)] = val;
    }
}

// K2: x [b][ic][y][x] f32 -> xt [b][y+1][x+1][ic] f16, zero halo border
__global__ __launch_bounds__(256) void transpose_x(const float* __restrict__ x,
                                                   _Float16* __restrict__ xt) {
    const int b  = blockIdx.y;
    const int yp = blockIdx.x;                 // padded row 0..129
    unsigned* rowbase = (unsigned*)(xt + ((size_t)(b * 130 + yp) * 130) * 64);
    const int tid = threadIdx.x;
    __shared__ float ls[64][129];
    if (yp == 0 || yp == 129) {
        for (int u = tid; u < 4160; u += 256) rowbase[u] = 0u;
        return;
    }
    for (int i = tid; i < 8192; i += 256) {
        int ic = i >> 7, xx = i & 127;
        ls[ic][xx] = x[(((size_t)b * 64 + ic) * 128 + (yp - 1)) * 128 + xx];
    }
    __syncthreads();
    for (int u = tid; u < 4160; u += 256) {
        int xp = u >> 5, icp = (u & 31) << 1;
        union { _Float16 h[2]; unsigned v; } pk;
        if (xp == 0 || xp == 129) pk.v = 0u;
        else { pk.h[0] = (_Float16)ls[icp][xp - 1]; pk.h[1] = (_Float16)ls[icp + 1][xp - 1]; }
        rowbase[u] = pk.v;
    }
}

// K3: implicit-GEMM conv. Block = 1 batch x 64 oc x 16x16 px, 4 waves.
// Wave: 4 oc-tiles x 4 px-rows, 16x16x32 f16 MFMA, K = 9 taps x 2 ic-halves.
__global__ __launch_bounds__(256, 3) void conv_mfma(const _Float16* __restrict__ xt,
                                                    const _Float16* __restrict__ wt,
                                                    const float* __restrict__ bias,
                                                    float* __restrict__ out) {
    __shared__ unsigned short xs[20992];       // 41984 B (2592 chunks + wave-tail pad)
    const int tid = threadIdx.x;
    const int w   = tid >> 6;
    const int l   = tid & 63;
    const int n   = l & 15;
    const int r4  = l >> 4;
    const int b   = blockIdx.z;
    const int ty0 = (blockIdx.x >> 3) * 16;
    const int tx0 = (blockIdx.x & 7) * 16;

    // ---- stage 18x18x64 f16 tile: linear LDS dest, pre-swizzled global source ----
    // chunk = 16 B; row = 18 px * 64 ic = 144 chunks; swizzle: blk ^= (pixel&7) on low 3 bits
    const _Float16* xbase = xt + (((size_t)b * 130 + ty0) * 130 + tx0) * 64;
    for (int it = 0; it < 11; ++it) {
        int cb = it * 256 + (tid & ~63);       // wave-uniform LDS chunk base
        if (cb > 2592) break;
        int c   = it * 256 + tid;              // this lane's dest chunk
        int px  = c >> 3;
        int sc  = (c & ~7) | ((c & 7) ^ (px & 7));   // inverse-swizzled source chunk
        int row = px / 18;
        int off = sc - row * 144;
        const _Float16* src = xbase + (size_t)row * (130 * 64) + off * 8;
        __builtin_amdgcn_global_load_lds(
            (const __attribute__((address_space(1))) void*)src,
            (__attribute__((address_space(3))) void*)((__attribute__((address_space(3))) char*)xs + cb * 16),
            16, 0, 0);
    }
    __syncthreads();

    f32x4 acc[4][4];
    #pragma unroll
    for (int i = 0; i < 4; ++i)
        #pragma unroll
        for (int j = 0; j < 4; ++j) acc[i][j] = (f32x4){0.f, 0.f, 0.f, 0.f};

    // lane-fixed weight base: oc = ot*16 + n (A row = lane&15), k-elems ic = h*32 + r4*8 + j
    const _Float16* wb = wt + (size_t)b * 9 * 4096 + n * 64 + r4 * 8;
    half8 a0, a1, a2, a3;
    a0 = *(const half8*)(wb);
    a1 = *(const half8*)(wb + 1024);
    a2 = *(const half8*)(wb + 2048);
    a3 = *(const half8*)(wb + 3072);

    for (int ks = 0; ks < 18; ++ks) {
        const int t  = ks >> 1, h = ks & 1;
        const int kh = t / 3, kw = t - 3 * kh;
        half8 n0, n1, n2, n3;
        const bool more = (ks + 1) < 18;
        if (more) {                            // prefetch next k-step's A frags
            int tn = (ks + 1) >> 1, hn = (ks + 1) & 1;
            const _Float16* wn = wb + tn * 4096 + hn * 32;
            n0 = *(const half8*)(wn);
            n1 = *(const half8*)(wn + 1024);
            n2 = *(const half8*)(wn + 2048);
            n3 = *(const half8*)(wn + 3072);
        }
        #pragma unroll
        for (int pg = 0; pg < 4; ++pg) {
            int p    = (w * 4 + pg + kh) * 18 + (n + kw);
            int byte = ((p * 128) + (h * 64) + (r4 * 16)) ^ ((p & 7) << 4);
            half8 bf = *(const half8*)((const char*)xs + byte);
            acc[0][pg] = __builtin_amdgcn_mfma_f32_16x16x32_f16(a0, bf, acc[0][pg], 0, 0, 0);
            acc[1][pg] = __builtin_amdgcn_mfma_f32_16x16x32_f16(a1, bf, acc[1][pg], 0, 0, 0);
            acc[2][pg] = __builtin_amdgcn_mfma_f32_16x16x32_f16(a2, bf, acc[2][pg], 0, 0, 0);
            acc[3][pg] = __builtin_amdgcn_mfma_f32_16x16x32_f16(a3, bf, acc[3][pg], 0, 0, 0);
        }
        if (more) { a0 = n0; a1 = n1; a2 = n2; a3 = n3; }
    }

    // epilogue: C/D layout col=lane&15 (px x), row=(lane>>4)*4+r (oc within tile)
    const int Y0 = ty0 + w * 4;
    #pragma unroll
    for (int ot = 0; ot < 4; ++ot) {
        f32x4 bv = *(const f32x4*)(bias + b * 64 + ot * 16 + r4 * 4);
        #pragma unroll
        for (int pg = 0; pg < 4; ++pg) {
            float* obase = out + (((size_t)(b * 64 + ot * 16 + r4 * 4) * 128) + Y0 + pg) * 128 + tx0 + n;
            obase[0]         = acc[ot][pg][0] + bv[0];
            obase[16384]     = acc[ot][pg][1] + bv[1];
            obase[2 * 16384] = acc[ot][pg][2] + bv[2];
            obase[3 * 16384] = acc[ot][pg][3] + bv[3];
        }
    }
}

// ============================ FALLBACK (R1, fp32) ============================

__global__ __launch_bounds__(256) void cond_gemm(const float* __restrict__ cond,
                                                 const float* __restrict__ Wc,
                                                 const float* __restrict__ bc,
                                                 float* __restrict__ wb) {
    __shared__ float condl[B_][CONDC + 1];
    __shared__ float Wl[16][CONDC + 1];
    const int tid = threadIdx.x;
    const int p0 = blockIdx.x * 16;
    for (int i = tid; i < B_ * CONDC; i += 256) condl[i >> 8][i & 255] = cond[i];
    for (int i = tid; i < 16 * CONDC; i += 256) {
        int pl = i >> 8, k = i & 255;
        Wl[pl][k] = Wc[(p0 + pl) * CONDC + k];
    }
    __syncthreads();
    const int pl = tid >> 4;
    const int b  = tid & 15;
    float acc = bc[p0 + pl];
    #pragma unroll 8
    for (int k = 0; k < CONDC; ++k) acc += Wl[pl][k] * condl[b][k];
    wb[b * NPARAM + p0 + pl] = tanhf(acc) * 5.0f;
}

#define TS  32
#define OG  8
#define ICC 8
__global__ __launch_bounds__(256) void conv_kernel(const float* __restrict__ x,
                                                   const float* __restrict__ wb,
                                                   float* __restrict__ out) {
    __shared__ float fxs[ICC][TS + 2][TS + 2];
    __shared__ float ws[OG][ICC][9];
    const int tid = threadIdx.x;
    const int b   = blockIdx.z;
    const int ocg = blockIdx.y * OG;
    const int tx0 = (blockIdx.x & 3) * TS;
    const int ty0 = (blockIdx.x >> 2) * TS;
    const int px  = (tid & 15) * 2;
    const int py  = (tid >> 4) * 2;
    float acc[OG][4];
    #pragma unroll
    for (int o = 0; o < OG; ++o)
        #pragma unroll
        for (int q = 0; q < 4; ++q) acc[o][q] = 0.0f;
    const float* wbase = wb + b * NPARAM;
    for (int ic0 = 0; ic0 < ICn; ic0 += ICC) {
        for (int i = tid; i < ICC * (TS + 2) * (TS + 2); i += 256) {
            int icl = i / ((TS + 2) * (TS + 2));
            int rem = i % ((TS + 2) * (TS + 2));
            int yy = rem / (TS + 2), xx = rem % (TS + 2);
            int gy = ty0 - 1 + yy, gx = tx0 - 1 + xx;
            float v = 0.0f;
            if (gy >= 0 && gy < Hn && gx >= 0 && gx < Wn)
                v = x[((b * ICn + ic0 + icl) * Hn + gy) * Wn + gx];
            fxs[icl][yy][xx] = v;
        }
        for (int i = tid; i < OG * ICC * 9; i += 256) {
            int o = i / (ICC * 9), rem = i % (ICC * 9);
            int icl = rem / 9, k = rem % 9;
            ws[o][icl][k] = wbase[((ocg + o) * ICn + ic0 + icl) * 9 + k];
        }
        __syncthreads();
        #pragma unroll
        for (int icl = 0; icl < ICC; ++icl) {
            float xv[4][4];
            #pragma unroll
            for (int dy = 0; dy < 4; ++dy)
                #pragma unroll
                for (int dx = 0; dx < 4; ++dx) xv[dy][dx] = fxs[icl][py + dy][px + dx];
            #pragma unroll
            for (int o = 0; o < OG; ++o)
                #pragma unroll
                for (int kh = 0; kh < 3; ++kh)
                    #pragma unroll
                    for (int kw = 0; kw < 3; ++kw) {
                        float wv = ws[o][icl][kh * 3 + kw];
                        acc[o][0] += xv[kh][kw] * wv;
                        acc[o][1] += xv[kh][kw + 1] * wv;
                        acc[o][2] += xv[kh + 1][kw] * wv;
                        acc[o][3] += xv[kh + 1][kw + 1] * wv;
                    }
        }
        __syncthreads();
    }
    #pragma unroll
    for (int o = 0; o < OG; ++o) {
        float bias = wbase[NW + ocg + o];
        int oc = ocg + o;
        float* obase = out + ((size_t)(b * OCn + oc) * Hn + (ty0 + py)) * Wn + tx0 + px;
        obase[0] = acc[o][0] + bias;
        obase[1] = acc[o][1] + bias;
        obase[Wn] = acc[o][2] + bias;
        obase[Wn + 1] = acc[o][3] + bias;
    }
}

// ============================ LAUNCH ============================

extern "C" void kernel_launch(void* const* d_in, const int* in_sizes, int n_in,
                              void* d_out, int out_size, void* d_ws, size_t ws_size,
                              hipStream_t stream) {
    const float* x    = (const float*)d_in[0];
    const float* cond = (const float*)d_in[1];
    const float* Wc   = (const float*)d_in[2];
    const float* bc   = (const float*)d_in[3];
    float* out = (float*)d_out;

    const size_t WT_BYTES = (size_t)B_ * 9 * 64 * 64 * 2;            // 1179648
    const size_t BIAS_OFF = WT_BYTES;                                 // f32 bias
    const size_t XT_OFF   = 1183744;                                  // 256-aligned
    const size_t XT_BYTES = (size_t)B_ * 130 * 130 * 64 * 2 + 32768;  // + staging-tail pad
    const size_t NEED     = XT_OFF + XT_BYTES;

    if (ws_size >= NEED) {
        _Float16* wt   = (_Float16*)d_ws;
        float*    bias = (float*)((char*)d_ws + BIAS_OFF);
        _Float16* xt   = (_Float16*)((char*)d_ws + XT_OFF);
        cond_gemm_f16<<<dim3(NPARAM / 16), 256, 0, stream>>>(cond, Wc, bc, wt, bias);
        transpose_x<<<dim3(130, B_), 256, 0, stream>>>(x, xt);
        conv_mfma<<<dim3(64, 1, B_), 256, 0, stream>>>(xt, wt, bias, out);
    } else {
        float* wbuf = (float*)d_ws;
        cond_gemm<<<dim3(NPARAM / 16), 256, 0, stream>>>(cond, Wc, bc, wbuf);
        conv_kernel<<<dim3(16, OCn / OG, B_), 256, 0, stream>>>(x, wbuf, out);
    }
}

// Round 3
// 85.372 us; speedup vs baseline: 5.4373x; 1.3669x over previous
//
#include <hip/hip_runtime.h>
#include <math.h>
#include <stdint.h>

#define B_    16
#define CONDC 256
#define ICn   64
#define OCn   64
#define Hn    128
#define Wn    128
#define NW    36864
#define NPARAM 36928

typedef _Float16 half8 __attribute__((ext_vector_type(8)));
typedef _Float16 half4 __attribute__((ext_vector_type(4)));
typedef float f32x4 __attribute__((ext_vector_type(4)));
typedef float f32x16 __attribute__((ext_vector_type(16)));

// ===================== PREP: transpose (blocks 0..2079) + cond MFMA-GEMM (2080..2656) =====================
__global__ __launch_bounds__(256) void prep(const float* __restrict__ x,
                                            const float* __restrict__ cond,
                                            const float* __restrict__ Wc,
                                            const float* __restrict__ bc,
                                            _Float16* __restrict__ xt,
                                            _Float16* __restrict__ wt,
                                            float* __restrict__ bias) {
    __shared__ float smem[8256];               // 33024 B (transpose) / reused as f16 cond (gemm)
    const int tid = threadIdx.x;
    int bx = blockIdx.x;

    if (bx < 2080) {
        // ---- transpose: x [b][ic][y][x] f32 -> xt [b][y+1][x+1][ic] f16, zero halo ----
        const int b  = bx / 130;
        const int yp = bx - b * 130;
        _Float16* rowhalf = xt + (size_t)(b * 130 + yp) * (130 * 64);
        if (yp == 0 || yp == 129) {
            half4 z = (half4){0, 0, 0, 0};
            for (int u = tid; u < 2080; u += 256) *(half4*)(rowhalf + u * 4) = z;
            return;
        }
        float* ls = smem;                      // [64][129]
        for (int i = tid; i < 2048; i += 256) {
            int ic = i >> 5;
            float4 v = ((const float4*)x)[(((size_t)(b * 64 + ic) * 128) + (yp - 1)) * 32 + (i & 31)];
            int xx = (i & 31) * 4;
            float* lr = ls + ic * 129 + xx;
            lr[0] = v.x; lr[1] = v.y; lr[2] = v.z; lr[3] = v.w;
        }
        __syncthreads();
        for (int u2 = tid; u2 < 2080; u2 += 256) {
            int xp = u2 >> 4, ic4 = (u2 & 15) << 2;
            half4 pk;
            if (xp == 0 || xp == 129) pk = (half4){0, 0, 0, 0};
            else {
                pk[0] = (_Float16)ls[(ic4    ) * 129 + xp - 1];
                pk[1] = (_Float16)ls[(ic4 + 1) * 129 + xp - 1];
                pk[2] = (_Float16)ls[(ic4 + 2) * 129 + xp - 1];
                pk[3] = (_Float16)ls[(ic4 + 3) * 129 + xp - 1];
            }
            *(half4*)(rowhalf + u2 * 4) = pk;
        }
    } else {
        // ---- cond-GEMM: wb[p][b] = tanh(Wc[p]·cond[b] + bc[p])*5 via 16x16x32 f16 MFMA ----
        const int g = bx - 2080;               // 0..576, 64 rows each
        _Float16* cl = (_Float16*)smem;        // [16][256] f16
        for (int i = tid; i < 1024; i += 256) {
            float4 v = ((const float4*)cond)[i];
            half4 pk = { (_Float16)v.x, (_Float16)v.y, (_Float16)v.z, (_Float16)v.w };
            *(half4*)(cl + i * 4) = pk;
        }
        __syncthreads();
        const int w = tid >> 6, l = tid & 63;
        const int n = l & 15, r4 = l >> 4;
        const int pb = g * 64 + w * 16;

        half8 bfr[8];
        #pragma unroll
        for (int kk = 0; kk < 8; ++kk)
            bfr[kk] = *(const half8*)(cl + n * 256 + kk * 32 + r4 * 8);

        f32x4 acc = (f32x4){0.f, 0.f, 0.f, 0.f};
        const float* wr = Wc + (size_t)(pb + n) * 256 + r4 * 8;
        #pragma unroll
        for (int kk = 0; kk < 8; ++kk) {
            float4 u0 = *(const float4*)(wr + kk * 32);
            float4 u1 = *(const float4*)(wr + kk * 32 + 4);
            half8 av;
            av[0] = (_Float16)u0.x; av[1] = (_Float16)u0.y; av[2] = (_Float16)u0.z; av[3] = (_Float16)u0.w;
            av[4] = (_Float16)u1.x; av[5] = (_Float16)u1.y; av[6] = (_Float16)u1.z; av[7] = (_Float16)u1.w;
            acc = __builtin_amdgcn_mfma_f32_16x16x32_f16(av, bfr[kk], acc, 0, 0, 0);
        }
        #pragma unroll
        for (int j = 0; j < 4; ++j) {
            int p = pb + r4 * 4 + j;           // C/D: col=lane&15 (batch), row=(lane>>4)*4+j (param)
            float v = tanhf(acc[j] + bc[p]) * 5.0f;
            if (p < NW) {
                int oc = p / 576, rem = p - oc * 576;
                int ic = rem / 9,  t  = rem - ic * 9;
                wt[(((size_t)n * 9 + t) * 64 + oc) * 64 + ic] = (_Float16)v;
            } else {
                bias[n * 64 + (p - NW)] = v;
            }
        }
    }
}

// ===================== CONV: barrier-free, wave-private LDS, 32x32x16 f16 MFMA =====================
// Block 256 thr = 4 waves. Wave: 64 oc x 32 px x 2 rows. LDS/wave: [4 rows][36 px][32 ic] f16 = 9216 B.
__global__ __launch_bounds__(256, 4) void conv_mfma32(const _Float16* __restrict__ xt,
                                                      const _Float16* __restrict__ wt,
                                                      const float* __restrict__ bias,
                                                      float* __restrict__ out) {
    __shared__ _Float16 xs[4 * 4608];          // 36864 B total
    const int tid = threadIdx.x;
    const int w = tid >> 6, l = tid & 63;
    const int px = l & 31, jj = l >> 5;
    const int b  = blockIdx.z;
    const int X0 = blockIdx.x * 32;
    const int Y0 = blockIdx.y * 8 + w * 2;     // padded top row of this wave's staged region
    const char* ldsb = (const char*)xs + w * 9216;
    const _Float16* xbase = xt + ((size_t)(b * 130 + Y0) * 130 + X0) * 64;

    // stage one ic-half: 4 rows x 36 px x 32 ic = 576 chunks of 16 B, linear dest,
    // source pre-swizzled (chunk-within-px m' = m ^ (px&3)) so reads can XOR-deswizzle.
    #define STAGE(hh) do {                                                              \
        _Pragma("unroll")                                                               \
        for (int it = 0; it < 9; ++it) {                                                \
            int d = it * 64 + l;                                                        \
            int row = (int)((unsigned)d / 144u);                                        \
            int c = d - row * 144;                                                      \
            int p = c >> 2, m = c & 3;                                                  \
            int mp = m ^ (p & 3);                                                       \
            const _Float16* src = xbase + (size_t)row * (130 * 64) + p * 64 + (hh) * 32 + mp * 8; \
            __builtin_amdgcn_global_load_lds(                                           \
                (const __attribute__((address_space(1))) void*)src,                     \
                (__attribute__((address_space(3))) void*)((__attribute__((address_space(3))) char*)xs + w * 9216 + it * 1024), \
                16, 0, 0);                                                              \
        } } while (0)

    const _Float16* wAl = wt + (size_t)b * 36864 + px * 64 + jj * 8;  // A row = l&31, k-base = jj*8
    half8 a0 = *(const half8*)(wAl);           // s=0: tap0, h0, iq0, ot0
    half8 a1 = *(const half8*)(wAl + 2048);    // ot1
    STAGE(0);
    asm volatile("s_waitcnt vmcnt(0)" ::: "memory");
    __builtin_amdgcn_sched_barrier(0);

    f32x16 acc00 = {}, acc01 = {}, acc10 = {}, acc11 = {};

    // step S in 0..35: h = S>=18, ss = S%18, tap = ss>>1 (kh,kw), iq = ss&1 (ic quarter)
    #define STEP(S, PREF) do {                                                          \
        int hh = (S) >= 18 ? 1 : 0;                                                     \
        int ss = (S) - hh * 18;                                                         \
        int tap = ss >> 1, iq = ss & 1;                                                 \
        int kh = tap / 3, kw = tap - kh * 3;                                            \
        int colb = px + kw;                                                             \
        const char* lp = ldsb + kh * 2304 + (colb << 6) + ((((iq << 1) + jj) ^ (colb & 3)) << 4); \
        half8 bf0 = *(const half8*)(lp);                                                \
        half8 bf1 = *(const half8*)(lp + 2304);                                         \
        half8 na0 = a0, na1 = a1;                                                       \
        if (PREF) {                                                                     \
            int sn = (S) + 1; int hn = sn >= 18 ? 1 : 0; int sy = sn - hn * 18;         \
            int tn = sy >> 1, qn = sy & 1;                                              \
            const _Float16* wn = wAl + tn * 4096 + hn * 32 + qn * 16;                   \
            na0 = *(const half8*)(wn);                                                  \
            na1 = *(const half8*)(wn + 2048);                                           \
        }                                                                               \
        acc00 = __builtin_amdgcn_mfma_f32_32x32x16_f16(a0, bf0, acc00, 0, 0, 0);        \
        acc01 = __builtin_amdgcn_mfma_f32_32x32x16_f16(a0, bf1, acc01, 0, 0, 0);        \
        acc10 = __builtin_amdgcn_mfma_f32_32x32x16_f16(a1, bf0, acc10, 0, 0, 0);        \
        acc11 = __builtin_amdgcn_mfma_f32_32x32x16_f16(a1, bf1, acc11, 0, 0, 0);        \
        a0 = na0; a1 = na1;                                                             \
    } while (0)

    #pragma unroll 6
    for (int s = 0; s < 18; ++s) STEP(s, 1);

    // restage same buffer with ic-half 1: all prior ds_reads must be complete first
    asm volatile("s_waitcnt lgkmcnt(0)" ::: "memory");
    __builtin_amdgcn_sched_barrier(0);
    STAGE(1);
    asm volatile("s_waitcnt vmcnt(0)" ::: "memory");
    __builtin_amdgcn_sched_barrier(0);

    #pragma unroll 6
    for (int s = 18; s < 36; ++s) STEP(s, s < 35);

    // epilogue: D col = lane&31 = px, row = (reg&3)+8*(reg>>2)+4*jj = oc within 32-tile
    const float* bb = bias + b * 64;
    const int ybase = blockIdx.y * 8 + w * 2;
    #define STORE(ACC, OT, R) do {                                                      \
        float* ob = out + (((size_t)(b * 64 + (OT) * 32) * 128) + ybase + (R)) * 128 + X0 + px; \
        _Pragma("unroll")                                                               \
        for (int reg = 0; reg < 16; ++reg) {                                            \
            int ocl = (reg & 3) + 8 * (reg >> 2) + 4 * jj;                              \
            ob[(size_t)ocl * 16384] = ACC[reg] + bb[(OT) * 32 + ocl];                   \
        } } while (0)
    STORE(acc00, 0, 0); STORE(acc01, 0, 1); STORE(acc10, 1, 0); STORE(acc11, 1, 1);
    #undef STAGE
    #undef STEP
    #undef STORE
}

// ===================== FALLBACK (fp32 direct, R1) =====================
__global__ __launch_bounds__(256) void cond_gemm(const float* __restrict__ cond,
                                                 const float* __restrict__ Wc,
                                                 const float* __restrict__ bc,
                                                 float* __restrict__ wb) {
    __shared__ float condl[B_][CONDC + 1];
    __shared__ float Wl[16][CONDC + 1];
    const int tid = threadIdx.x;
    const int p0 = blockIdx.x * 16;
    for (int i = tid; i < B_ * CONDC; i += 256) condl[i >> 8][i & 255] = cond[i];
    for (int i = tid; i < 16 * CONDC; i += 256) {
        int pl = i >> 8, k = i & 255;
        Wl[pl][k] = Wc[(p0 + pl) * CONDC + k];
    }
    __syncthreads();
    const int pl = tid >> 4;
    const int b  = tid & 15;
    float acc = bc[p0 + pl];
    #pragma unroll 8
    for (int k = 0; k < CONDC; ++k) acc += Wl[pl][k] * condl[b][k];
    wb[b * NPARAM + p0 + pl] = tanhf(acc) * 5.0f;
}

#define TS  32
#define OG  8
#define ICC 8
__global__ __launch_bounds__(256) void conv_kernel(const float* __restrict__ x,
                                                   const float* __restrict__ wb,
                                                   float* __restrict__ out) {
    __shared__ float fxs[ICC][TS + 2][TS + 2];
    __shared__ float ws[OG][ICC][9];
    const int tid = threadIdx.x;
    const int b   = blockIdx.z;
    const int ocg = blockIdx.y * OG;
    const int tx0 = (blockIdx.x & 3) * TS;
    const int ty0 = (blockIdx.x >> 2) * TS;
    const int px  = (tid & 15) * 2;
    const int py  = (tid >> 4) * 2;
    float acc[OG][4];
    #pragma unroll
    for (int o = 0; o < OG; ++o)
        #pragma unroll
        for (int q = 0; q < 4; ++q) acc[o][q] = 0.0f;
    const float* wbase = wb + b * NPARAM;
    for (int ic0 = 0; ic0 < ICn; ic0 += ICC) {
        for (int i = tid; i < ICC * (TS + 2) * (TS + 2); i += 256) {
            int icl = i / ((TS + 2) * (TS + 2));
            int rem = i % ((TS + 2) * (TS + 2));
            int yy = rem / (TS + 2), xx = rem % (TS + 2);
            int gy = ty0 - 1 + yy, gx = tx0 - 1 + xx;
            float v = 0.0f;
            if (gy >= 0 && gy < Hn && gx >= 0 && gx < Wn)
                v = x[((b * ICn + ic0 + icl) * Hn + gy) * Wn + gx];
            fxs[icl][yy][xx] = v;
        }
        for (int i = tid; i < OG * ICC * 9; i += 256) {
            int o = i / (ICC * 9), rem = i % (ICC * 9);
            int icl = rem / 9, k = rem % 9;
            ws[o][icl][k] = wbase[((ocg + o) * ICn + ic0 + icl) * 9 + k];
        }
        __syncthreads();
        #pragma unroll
        for (int icl = 0; icl < ICC; ++icl) {
            float xv[4][4];
            #pragma unroll
            for (int dy = 0; dy < 4; ++dy)
                #pragma unroll
                for (int dx = 0; dx < 4; ++dx) xv[dy][dx] = fxs[icl][py + dy][px + dx];
            #pragma unroll
            for (int o = 0; o < OG; ++o)
                #pragma unroll
                for (int kh = 0; kh < 3; ++kh)
                    #pragma unroll
                    for (int kw = 0; kw < 3; ++kw) {
                        float wv = ws[o][icl][kh * 3 + kw];
                        acc[o][0] += xv[kh][kw] * wv;
                        acc[o][1] += xv[kh][kw + 1] * wv;
                        acc[o][2] += xv[kh + 1][kw] * wv;
                        acc[o][3] += xv[kh + 1][kw + 1] * wv;
                    }
        }
        __syncthreads();
    }
    #pragma unroll
    for (int o = 0; o < OG; ++o) {
        float bias = wbase[NW + ocg + o];
        int oc = ocg + o;
        float* obase = out + ((size_t)(b * OCn + oc) * Hn + (ty0 + py)) * Wn + tx0 + px;
        obase[0] = acc[o][0] + bias;
        obase[1] = acc[o][1] + bias;
        obase[Wn] = acc[o][2] + bias;
        obase[Wn + 1] = acc[o][3] + bias;
    }
}

// ===================== LAUNCH =====================
extern "C" void kernel_launch(void* const* d_in, const int* in_sizes, int n_in,
                              void* d_out, int out_size, void* d_ws, size_t ws_size,
                              hipStream_t stream) {
    const float* x    = (const float*)d_in[0];
    const float* cond = (const float*)d_in[1];
    const float* Wc   = (const float*)d_in[2];
    const float* bc   = (const float*)d_in[3];
    float* out = (float*)d_out;

    const size_t WT_BYTES = (size_t)B_ * 9 * 64 * 64 * 2;            // 1179648
    const size_t BIAS_OFF = WT_BYTES;
    const size_t XT_OFF   = 1183744;                                  // 256-aligned
    const size_t XT_BYTES = (size_t)B_ * 130 * 130 * 64 * 2 + 32768;  // + stage-overread pad
    const size_t NEED     = XT_OFF + XT_BYTES;

    if (ws_size >= NEED) {
        _Float16* wt   = (_Float16*)d_ws;
        float*    bias = (float*)((char*)d_ws + BIAS_OFF);
        _Float16* xt   = (_Float16*)((char*)d_ws + XT_OFF);
        prep<<<dim3(2080 + 577), 256, 0, stream>>>(x, cond, Wc, bc, xt, wt, bias);
        conv_mfma32<<<dim3(4, 16, 16), 256, 0, stream>>>(xt, wt, bias, out);
    } else {
        float* wbuf = (float*)d_ws;
        cond_gemm<<<dim3(NPARAM / 16), 256, 0, stream>>>(cond, Wc, bc, wbuf);
        conv_kernel<<<dim3(16, OCn / OG, B_), 256, 0, stream>>>(x, wbuf, out);
    }
}

// Round 4
// 70.094 us; speedup vs baseline: 6.6224x; 1.2180x over previous
//
#include <hip/hip_runtime.h>
#include <math.h>
#include <stdint.h>

#define B_    16
#define CONDC 256
#define ICn   64
#define OCn   64
#define Hn    128
#define Wn    128
#define NW    36864
#define NPARAM 36928

typedef _Float16 half8 __attribute__((ext_vector_type(8)));
typedef _Float16 half4 __attribute__((ext_vector_type(4)));
typedef float f32x4 __attribute__((ext_vector_type(4)));
typedef float f32x16 __attribute__((ext_vector_type(16)));

// ===================== PREP: transpose (blocks 0..2079) + cond MFMA-GEMM (2080..2656) =====================
// wt layout: [b][icq(4)][tap(9)][oc(64)][ic16] f16
__global__ __launch_bounds__(256) void prep(const float* __restrict__ x,
                                            const float* __restrict__ cond,
                                            const float* __restrict__ Wc,
                                            const float* __restrict__ bc,
                                            _Float16* __restrict__ xt,
                                            _Float16* __restrict__ wt,
                                            float* __restrict__ bias) {
    __shared__ float smem[8256];
    const int tid = threadIdx.x;
    int bx = blockIdx.x;

    if (bx < 2080) {
        // x [b][ic][y][x] f32 -> xt [b][y+1][x+1][64 ic] f16, zero halo
        const int b  = bx / 130;
        const int yp = bx - b * 130;
        _Float16* rowhalf = xt + (size_t)(b * 130 + yp) * (130 * 64);
        if (yp == 0 || yp == 129) {
            half4 z = (half4){0, 0, 0, 0};
            for (int u = tid; u < 2080; u += 256) *(half4*)(rowhalf + u * 4) = z;
            return;
        }
        float* ls = smem;                      // [64][129]
        for (int i = tid; i < 2048; i += 256) {
            int ic = i >> 5;
            float4 v = ((const float4*)x)[(((size_t)(b * 64 + ic) * 128) + (yp - 1)) * 32 + (i & 31)];
            int xx = (i & 31) * 4;
            float* lr = ls + ic * 129 + xx;
            lr[0] = v.x; lr[1] = v.y; lr[2] = v.z; lr[3] = v.w;
        }
        __syncthreads();
        for (int u2 = tid; u2 < 2080; u2 += 256) {
            int xp = u2 >> 4, ic4 = (u2 & 15) << 2;
            half4 pk;
            if (xp == 0 || xp == 129) pk = (half4){0, 0, 0, 0};
            else {
                pk[0] = (_Float16)ls[(ic4    ) * 129 + xp - 1];
                pk[1] = (_Float16)ls[(ic4 + 1) * 129 + xp - 1];
                pk[2] = (_Float16)ls[(ic4 + 2) * 129 + xp - 1];
                pk[3] = (_Float16)ls[(ic4 + 3) * 129 + xp - 1];
            }
            *(half4*)(rowhalf + u2 * 4) = pk;
        }
    } else {
        // cond-GEMM: wb[p][b] = tanh(Wc[p]·cond[b] + bc[p])*5 via 16x16x32 f16 MFMA
        const int g = bx - 2080;
        _Float16* cl = (_Float16*)smem;        // [16 batch][256] f16
        for (int i = tid; i < 1024; i += 256) {
            float4 v = ((const float4*)cond)[i];
            half4 pk = { (_Float16)v.x, (_Float16)v.y, (_Float16)v.z, (_Float16)v.w };
            *(half4*)(cl + i * 4) = pk;
        }
        __syncthreads();
        const int w = tid >> 6, l = tid & 63;
        const int n = l & 15, r4 = l >> 4;
        const int pb = g * 64 + w * 16;

        half8 bfr[8];
        #pragma unroll
        for (int kk = 0; kk < 8; ++kk)
            bfr[kk] = *(const half8*)(cl + n * 256 + kk * 32 + r4 * 8);

        f32x4 acc = (f32x4){0.f, 0.f, 0.f, 0.f};
        const float* wr = Wc + (size_t)(pb + n) * 256 + r4 * 8;
        #pragma unroll
        for (int kk = 0; kk < 8; ++kk) {
            float4 u0 = *(const float4*)(wr + kk * 32);
            float4 u1 = *(const float4*)(wr + kk * 32 + 4);
            half8 av;
            av[0] = (_Float16)u0.x; av[1] = (_Float16)u0.y; av[2] = (_Float16)u0.z; av[3] = (_Float16)u0.w;
            av[4] = (_Float16)u1.x; av[5] = (_Float16)u1.y; av[6] = (_Float16)u1.z; av[7] = (_Float16)u1.w;
            acc = __builtin_amdgcn_mfma_f32_16x16x32_f16(av, bfr[kk], acc, 0, 0, 0);
        }
        #pragma unroll
        for (int j = 0; j < 4; ++j) {
            int p = pb + r4 * 4 + j;           // C/D: col=lane&15 (batch), row=(lane>>4)*4+j (param)
            float v = tanhf(acc[j] + bc[p]) * 5.0f;
            if (p < NW) {
                int oc = p / 576, rem = p - oc * 576;
                int ic = rem / 9,  t  = rem - ic * 9;
                int icq = ic >> 4, icl = ic & 15;
                wt[((((size_t)n * 4 + icq) * 9 + t) * 64 + oc) * 16 + icl] = (_Float16)v;
            } else {
                bias[n * 64 + (p - NW)] = v;
            }
        }
    }
}

// ===================== CONV v4: A-in-regs, shared swizzled LDS B, counted vmcnt =====================
// Block 512 thr = 8 waves (2 oc-halves x 4 row-groups). Covers b x 64oc x 32px x 16 rows.
// K = 4 ic16-slices x 9 taps. LDS: double-buffered [18 rows][36 px][16 ic] f16.
__global__ __launch_bounds__(512, 2) void conv_v4(const _Float16* __restrict__ xt,
                                                  const _Float16* __restrict__ wt,
                                                  const float* __restrict__ bias,
                                                  float* __restrict__ out) {
    __shared__ _Float16 xs[2][12288];          // 2 x 24576 B (1296 used chunks + stage tail)
    const int tid = threadIdx.x;
    const int l   = tid & 63;
    const int w   = tid >> 6;
    const int px  = l & 31;
    const int jj  = l >> 5;
    const int ot  = w & 1;                     // oc half
    const int rg  = w >> 1;                    // row group (4 rows each)
    const int b   = blockIdx.z;
    const int X0  = blockIdx.x * 32;
    const int Y0g = blockIdx.y * 16;

    const _Float16* xbase = xt + ((size_t)(b * 130 + Y0g) * 130 + X0) * 64;
    const _Float16* wbat  = wt + (size_t)b * 36864 + (size_t)(ot * 32 + px) * 16 + jj * 8;

    // lane-const swizzled LDS byte offsets per kw; swz(c) = c ^ ((c>>3)&7) (involution)
    int offkw[3];
    #pragma unroll
    for (int kw = 0; kw < 3; ++kw) {
        int c = (px + kw) * 2 + jj;
        offkw[kw] = (c ^ ((c >> 3) & 7)) * 16;
    }
    const int Lb = rg * 4;

    // stage ic16-slice ICQ into buffer BUF: 18 rows x 72 chunks(16B); linear LDS dest,
    // inverse-swizzled source (rule 21). All waves issue exactly 3 gload_lds (tail clamped).
    #define STAGEQ(ICQ, BUF) do {                                                       \
        _Pragma("unroll")                                                               \
        for (int it = 0; it < 3; ++it) {                                                \
            int d  = it * 512 + tid;                                                    \
            int dc = d < 1296 ? d : 1295;                                               \
            int row = (int)((unsigned)dc / 72u);                                        \
            int c   = dc - row * 72;                                                    \
            int cs  = c ^ ((c >> 3) & 7);                                               \
            const _Float16* src = xbase + (size_t)row * 8320 + (cs >> 1) * 64           \
                                + (ICQ) * 16 + (cs & 1) * 8;                            \
            __builtin_amdgcn_global_load_lds(                                           \
                (const __attribute__((address_space(1))) void*)src,                     \
                (__attribute__((address_space(3))) void*)((__attribute__((address_space(3))) char*)xs + (BUF) * 24576 + (it * 512 + (tid & ~63)) * 16), \
                16, 0, 0);                                                              \
        } } while (0)

    STAGEQ(0, 0);
    half8 A[2][9];
    #pragma unroll
    for (int t = 0; t < 9; ++t) A[0][t] = *(const half8*)(wbat + t * 1024);

    f32x16 acc[4];
    #pragma unroll
    for (int r = 0; r < 4; ++r) acc[r] = (f32x16){};

    #pragma unroll
    for (int icq = 0; icq < 4; ++icq) {
        const int cur = icq & 1;
        if (icq < 3) {
            STAGEQ(icq + 1, cur ^ 1);
            asm volatile("s_waitcnt vmcnt(3)" ::: "memory");  // drain slice icq (+ older A); keep next stage in flight
        } else {
            asm volatile("s_waitcnt vmcnt(0)" ::: "memory");
        }
        __builtin_amdgcn_sched_barrier(0);
        __builtin_amdgcn_s_barrier();                         // raw barrier: no implicit drain
        __builtin_amdgcn_sched_barrier(0);

        if (icq < 3) {                                        // prefetch next slice's A into other regs
            #pragma unroll
            for (int t = 0; t < 9; ++t)
                A[cur ^ 1][t] = *(const half8*)(wbat + ((icq + 1) * 9 + t) * 1024);
        }

        const char* bufb = (const char*)xs + cur * 24576;
        #pragma unroll
        for (int kw = 0; kw < 3; ++kw) {
            half8 Bf[6];
            #pragma unroll
            for (int iy = 0; iy < 6; ++iy)
                Bf[iy] = *(const half8*)(bufb + (Lb + iy) * 1152 + offkw[kw]);
            #pragma unroll
            for (int iy = 0; iy < 6; ++iy) {
                #pragma unroll
                for (int kh = 0; kh < 3; ++kh) {
                    const int r = iy - kh;                    // input row iy feeds output rows iy-kh
                    if (r >= 0 && r < 4)
                        acc[r] = __builtin_amdgcn_mfma_f32_32x32x16_f16(A[cur][kh * 3 + kw], Bf[iy], acc[r], 0, 0, 0);
                }
            }
        }
        asm volatile("s_waitcnt lgkmcnt(0)" ::: "memory");    // reads done before others overwrite
        __builtin_amdgcn_sched_barrier(0);
        __builtin_amdgcn_s_barrier();
        __builtin_amdgcn_sched_barrier(0);
    }
    #undef STAGEQ

    // epilogue: D col = lane&31 = px, oc-within-32 = (reg&3)+8*(reg>>2)+4*jj
    const float* bb = bias + b * 64;
    #pragma unroll
    for (int r = 0; r < 4; ++r) {
        const int yo = Y0g + Lb + r;
        float* ob = out + (((size_t)(b * 64 + ot * 32)) * 128 + yo) * 128 + X0 + px;
        #pragma unroll
        for (int reg = 0; reg < 16; ++reg) {
            const int ocl = (reg & 3) + 8 * (reg >> 2) + 4 * jj;
            ob[(size_t)ocl * 16384] = acc[r][reg] + bb[ot * 32 + ocl];
        }
    }
}

// ===================== FALLBACK (fp32 direct, R1) =====================
__global__ __launch_bounds__(256) void cond_gemm(const float* __restrict__ cond,
                                                 const float* __restrict__ Wc,
                                                 const float* __restrict__ bc,
                                                 float* __restrict__ wb) {
    __shared__ float condl[B_][CONDC + 1];
    __shared__ float Wl[16][CONDC + 1];
    const int tid = threadIdx.x;
    const int p0 = blockIdx.x * 16;
    for (int i = tid; i < B_ * CONDC; i += 256) condl[i >> 8][i & 255] = cond[i];
    for (int i = tid; i < 16 * CONDC; i += 256) {
        int pl = i >> 8, k = i & 255;
        Wl[pl][k] = Wc[(p0 + pl) * CONDC + k];
    }
    __syncthreads();
    const int pl = tid >> 4;
    const int b  = tid & 15;
    float acc = bc[p0 + pl];
    #pragma unroll 8
    for (int k = 0; k < CONDC; ++k) acc += Wl[pl][k] * condl[b][k];
    wb[b * NPARAM + p0 + pl] = tanhf(acc) * 5.0f;
}

#define TS  32
#define OG  8
#define ICC 8
__global__ __launch_bounds__(256) void conv_kernel(const float* __restrict__ x,
                                                   const float* __restrict__ wb,
                                                   float* __restrict__ out) {
    __shared__ float fxs[ICC][TS + 2][TS + 2];
    __shared__ float ws[OG][ICC][9];
    const int tid = threadIdx.x;
    const int b   = blockIdx.z;
    const int ocg = blockIdx.y * OG;
    const int tx0 = (blockIdx.x & 3) * TS;
    const int ty0 = (blockIdx.x >> 2) * TS;
    const int px  = (tid & 15) * 2;
    const int py  = (tid >> 4) * 2;
    float acc[OG][4];
    #pragma unroll
    for (int o = 0; o < OG; ++o)
        #pragma unroll
        for (int q = 0; q < 4; ++q) acc[o][q] = 0.0f;
    const float* wbase = wb + b * NPARAM;
    for (int ic0 = 0; ic0 < ICn; ic0 += ICC) {
        for (int i = tid; i < ICC * (TS + 2) * (TS + 2); i += 256) {
            int icl = i / ((TS + 2) * (TS + 2));
            int rem = i % ((TS + 2) * (TS + 2));
            int yy = rem / (TS + 2), xx = rem % (TS + 2);
            int gy = ty0 - 1 + yy, gx = tx0 - 1 + xx;
            float v = 0.0f;
            if (gy >= 0 && gy < Hn && gx >= 0 && gx < Wn)
                v = x[((b * ICn + ic0 + icl) * Hn + gy) * Wn + gx];
            fxs[icl][yy][xx] = v;
        }
        for (int i = tid; i < OG * ICC * 9; i += 256) {
            int o = i / (ICC * 9), rem = i % (ICC * 9);
            int icl = rem / 9, k = rem % 9;
            ws[o][icl][k] = wbase[((ocg + o) * ICn + ic0 + icl) * 9 + k];
        }
        __syncthreads();
        #pragma unroll
        for (int icl = 0; icl < ICC; ++icl) {
            float xv[4][4];
            #pragma unroll
            for (int dy = 0; dy < 4; ++dy)
                #pragma unroll
                for (int dx = 0; dx < 4; ++dx) xv[dy][dx] = fxs[icl][py + dy][px + dx];
            #pragma unroll
            for (int o = 0; o < OG; ++o)
                #pragma unroll
                for (int kh = 0; kh < 3; ++kh)
                    #pragma unroll
                    for (int kw = 0; kw < 3; ++kw) {
                        float wv = ws[o][icl][kh * 3 + kw];
                        acc[o][0] += xv[kh][kw] * wv;
                        acc[o][1] += xv[kh][kw + 1] * wv;
                        acc[o][2] += xv[kh + 1][kw] * wv;
                        acc[o][3] += xv[kh + 1][kw + 1] * wv;
                    }
        }
        __syncthreads();
    }
    #pragma unroll
    for (int o = 0; o < OG; ++o) {
        float bias = wbase[NW + ocg + o];
        int oc = ocg + o;
        float* obase = out + ((size_t)(b * OCn + oc) * Hn + (ty0 + py)) * Wn + tx0 + px;
        obase[0] = acc[o][0] + bias;
        obase[1] = acc[o][1] + bias;
        obase[Wn] = acc[o][2] + bias;
        obase[Wn + 1] = acc[o][3] + bias;
    }
}

// ===================== LAUNCH =====================
extern "C" void kernel_launch(void* const* d_in, const int* in_sizes, int n_in,
                              void* d_out, int out_size, void* d_ws, size_t ws_size,
                              hipStream_t stream) {
    const float* x    = (const float*)d_in[0];
    const float* cond = (const float*)d_in[1];
    const float* Wc   = (const float*)d_in[2];
    const float* bc   = (const float*)d_in[3];
    float* out = (float*)d_out;

    const size_t WT_BYTES = (size_t)B_ * 9 * 64 * 64 * 2;            // 1179648
    const size_t BIAS_OFF = WT_BYTES;
    const size_t XT_OFF   = 1183744;                                  // 256-aligned
    const size_t XT_BYTES = (size_t)B_ * 130 * 130 * 64 * 2 + 32768;  // + stage-overread pad
    const size_t NEED     = XT_OFF + XT_BYTES;

    if (ws_size >= NEED) {
        _Float16* wt   = (_Float16*)d_ws;
        float*    bias = (float*)((char*)d_ws + BIAS_OFF);
        _Float16* xt   = (_Float16*)((char*)d_ws + XT_OFF);
        prep<<<dim3(2080 + 577), 256, 0, stream>>>(x, cond, Wc, bc, xt, wt, bias);
        conv_v4<<<dim3(4, 8, 16), 512, 0, stream>>>(xt, wt, bias, out);
    } else {
        float* wbuf = (float*)d_ws;
        cond_gemm<<<dim3(NPARAM / 16), 256, 0, stream>>>(cond, Wc, bc, wbuf);
        conv_kernel<<<dim3(16, OCn / OG, B_), 256, 0, stream>>>(x, wbuf, out);
    }
}

// Round 5
// 67.787 us; speedup vs baseline: 6.8477x; 1.0340x over previous
//
#include <hip/hip_runtime.h>
#include <math.h>
#include <stdint.h>

#define B_    16
#define CONDC 256
#define ICn   64
#define OCn   64
#define Hn    128
#define Wn    128
#define NW    36864
#define NPARAM 36928

typedef _Float16 half8 __attribute__((ext_vector_type(8)));
typedef _Float16 half4 __attribute__((ext_vector_type(4)));
typedef float f32x4 __attribute__((ext_vector_type(4)));
typedef float f32x16 __attribute__((ext_vector_type(16)));

__device__ inline unsigned pk2(float a, float b) {
    union { _Float16 h[2]; unsigned u; } q;
    q.h[0] = (_Float16)a; q.h[1] = (_Float16)b;
    return q.u;
}

// ===================== PREP v2 =====================
// blocks [0,2048): transpose interior rows  (b = bx>>7, y = bx&127)
// blocks [2048,2080): zero halo rows        (b = q>>1, yp = (q&1)?129:0)
// blocks [2080,3234): cond-GEMM, 32 params/block, Wc staged coalesced
// wt layout: [b][icq(4)][tap(9)][oc(64)][ic16] f16
__global__ __launch_bounds__(256, 8) void prep(const float* __restrict__ x,
                                               const float* __restrict__ cond,
                                               const float* __restrict__ Wc,
                                               const float* __restrict__ bc,
                                               _Float16* __restrict__ xt,
                                               _Float16* __restrict__ wt,
                                               float* __restrict__ bias) {
    __shared__ unsigned smem[4352];            // 17408 B, reused by both branches
    const int tid = threadIdx.x;
    const int bx  = blockIdx.x;

    if (bx < 2048) {
        // ---- transpose: x[b][ic][y][:] f32 -> xt[b][y+1][1..128][ic] f16 ----
        const int b = bx >> 7, y = bx & 127, yp = y + 1;
        const float* xrow = x + (size_t)b * 1048576 + (size_t)y * 128;   // + ic*16384
        _Float16* rowhalf = xt + (size_t)(b * 130 + yp) * 8320;
        unsigned* ls = smem;                   // [icp(32)][130] u32 (ic pair packed)
        #pragma unroll
        for (int t = 0; t < 4; ++t) {
            int u = t * 256 + tid;             // 0..1023 = 32 icp x 32 xg
            int icp = u >> 5, xg = u & 31;
            const float* r0 = xrow + (size_t)(2 * icp) * 16384;
            float4 v0 = *((const float4*)r0 + xg);
            float4 v1 = *((const float4*)(r0 + 16384) + xg);
            unsigned* dst = ls + icp * 130 + 4 * xg;
            uint2 w01 = make_uint2(pk2(v0.x, v1.x), pk2(v0.y, v1.y));
            uint2 w23 = make_uint2(pk2(v0.z, v1.z), pk2(v0.w, v1.w));
            *(uint2*)(dst)     = w01;
            *(uint2*)(dst + 2) = w23;
        }
        __syncthreads();
        #pragma unroll
        for (int t = 0; t < 5; ++t) {
            int u = t * 256 + tid;             // 0..1039 = 130 xp x 8 icgroups
            if (u < 1040) {
                int xp = u >> 3, g = u & 7;
                uint4 val = make_uint4(0u, 0u, 0u, 0u);
                if (xp > 0 && xp < 129) {
                    int xx = xp - 1;
                    val.x = ls[(4 * g + 0) * 130 + xx];
                    val.y = ls[(4 * g + 1) * 130 + xx];
                    val.z = ls[(4 * g + 2) * 130 + xx];
                    val.w = ls[(4 * g + 3) * 130 + xx];
                }
                *(uint4*)(rowhalf + (size_t)u * 8) = val;
            }
        }
    } else if (bx < 2080) {
        // ---- zero halo rows (yp = 0 / 129) ----
        const int q = bx - 2048;
        const int b = q >> 1, yp = (q & 1) ? 129 : 0;
        _Float16* rowhalf = xt + (size_t)(b * 130 + yp) * 8320;
        uint4 z = make_uint4(0u, 0u, 0u, 0u);
        for (int u = tid; u < 1040; u += 256)
            *(uint4*)(rowhalf + (size_t)u * 8) = z;
    } else {
        // ---- cond-GEMM: 32 params/block; Wc staged coalesced into f16 LDS ----
        const int g = bx - 2080;               // 0..1153
        const int pbase = g * 32;
        _Float16* wl = (_Float16*)smem;        // [32][272] f16 (256 data + 16 pad)
        #pragma unroll
        for (int t = 0; t < 8; ++t) {
            int v = t * 256 + tid;             // 2048 float4 = 32 rows x 64
            int pl = v >> 6, kg = v & 63;
            float4 q4 = *((const float4*)(Wc + (size_t)(pbase + pl) * 256) + kg);
            half4 h = { (_Float16)q4.x, (_Float16)q4.y, (_Float16)q4.z, (_Float16)q4.w };
            *(half4*)(wl + pl * 272 + kg * 4) = h;
        }
        __syncthreads();
        const int w = tid >> 6;
        if (w < 2) {
            const int l = tid & 63, n = l & 15, r4 = l >> 4;
            const _Float16* arow = wl + (w * 16 + n) * 272 + r4 * 8;
            const float*    crow = cond + n * 256 + r4 * 8;
            f32x4 acc = (f32x4){0.f, 0.f, 0.f, 0.f};
            #pragma unroll
            for (int kk = 0; kk < 8; ++kk) {
                half8 av = *(const half8*)(arow + kk * 32);
                float4 u0 = *(const float4*)(crow + kk * 32);
                float4 u1 = *(const float4*)(crow + kk * 32 + 4);
                half8 bv;
                bv[0] = (_Float16)u0.x; bv[1] = (_Float16)u0.y; bv[2] = (_Float16)u0.z; bv[3] = (_Float16)u0.w;
                bv[4] = (_Float16)u1.x; bv[5] = (_Float16)u1.y; bv[6] = (_Float16)u1.z; bv[7] = (_Float16)u1.w;
                acc = __builtin_amdgcn_mfma_f32_16x16x32_f16(av, bv, acc, 0, 0, 0);
            }
            #pragma unroll
            for (int j = 0; j < 4; ++j) {
                int p = pbase + w * 16 + r4 * 4 + j;   // C/D: col=lane&15 (batch), row=(lane>>4)*4+j
                float v = tanhf(acc[j] + bc[p]) * 5.0f;
                if (p < NW) {
                    int oc = p / 576, rem = p - oc * 576;
                    int ic = rem / 9,  t  = rem - ic * 9;
                    int icq = ic >> 4, icl = ic & 15;
                    wt[((((size_t)n * 4 + icq) * 9 + t) * 64 + oc) * 16 + icl] = (_Float16)v;
                } else {
                    bias[n * 64 + (p - NW)] = v;
                }
            }
        }
    }
}

// ===================== CONV v4 (unchanged from R4): A-in-regs, shared swizzled LDS B, counted vmcnt =====================
__global__ __launch_bounds__(512, 2) void conv_v4(const _Float16* __restrict__ xt,
                                                  const _Float16* __restrict__ wt,
                                                  const float* __restrict__ bias,
                                                  float* __restrict__ out) {
    __shared__ _Float16 xs[2][12288];          // 2 x 24576 B
    const int tid = threadIdx.x;
    const int l   = tid & 63;
    const int w   = tid >> 6;
    const int px  = l & 31;
    const int jj  = l >> 5;
    const int ot  = w & 1;
    const int rg  = w >> 1;
    const int b   = blockIdx.z;
    const int X0  = blockIdx.x * 32;
    const int Y0g = blockIdx.y * 16;

    const _Float16* xbase = xt + ((size_t)(b * 130 + Y0g) * 130 + X0) * 64;
    const _Float16* wbat  = wt + (size_t)b * 36864 + (size_t)(ot * 32 + px) * 16 + jj * 8;

    int offkw[3];
    #pragma unroll
    for (int kw = 0; kw < 3; ++kw) {
        int c = (px + kw) * 2 + jj;
        offkw[kw] = (c ^ ((c >> 3) & 7)) * 16;
    }
    const int Lb = rg * 4;

    #define STAGEQ(ICQ, BUF) do {                                                       \
        _Pragma("unroll")                                                               \
        for (int it = 0; it < 3; ++it) {                                                \
            int d  = it * 512 + tid;                                                    \
            int dc = d < 1296 ? d : 1295;                                               \
            int row = (int)((unsigned)dc / 72u);                                        \
            int c   = dc - row * 72;                                                    \
            int cs  = c ^ ((c >> 3) & 7);                                               \
            const _Float16* src = xbase + (size_t)row * 8320 + (cs >> 1) * 64           \
                                + (ICQ) * 16 + (cs & 1) * 8;                            \
            __builtin_amdgcn_global_load_lds(                                           \
                (const __attribute__((address_space(1))) void*)src,                     \
                (__attribute__((address_space(3))) void*)((__attribute__((address_space(3))) char*)xs + (BUF) * 24576 + (it * 512 + (tid & ~63)) * 16), \
                16, 0, 0);                                                              \
        } } while (0)

    STAGEQ(0, 0);
    half8 A[2][9];
    #pragma unroll
    for (int t = 0; t < 9; ++t) A[0][t] = *(const half8*)(wbat + t * 1024);

    f32x16 acc[4];
    #pragma unroll
    for (int r = 0; r < 4; ++r) acc[r] = (f32x16){};

    #pragma unroll
    for (int icq = 0; icq < 4; ++icq) {
        const int cur = icq & 1;
        if (icq < 3) {
            STAGEQ(icq + 1, cur ^ 1);
            asm volatile("s_waitcnt vmcnt(3)" ::: "memory");
        } else {
            asm volatile("s_waitcnt vmcnt(0)" ::: "memory");
        }
        __builtin_amdgcn_sched_barrier(0);
        __builtin_amdgcn_s_barrier();
        __builtin_amdgcn_sched_barrier(0);

        if (icq < 3) {
            #pragma unroll
            for (int t = 0; t < 9; ++t)
                A[cur ^ 1][t] = *(const half8*)(wbat + ((icq + 1) * 9 + t) * 1024);
        }

        const char* bufb = (const char*)xs + cur * 24576;
        #pragma unroll
        for (int kw = 0; kw < 3; ++kw) {
            half8 Bf[6];
            #pragma unroll
            for (int iy = 0; iy < 6; ++iy)
                Bf[iy] = *(const half8*)(bufb + (Lb + iy) * 1152 + offkw[kw]);
            #pragma unroll
            for (int iy = 0; iy < 6; ++iy) {
                #pragma unroll
                for (int kh = 0; kh < 3; ++kh) {
                    const int r = iy - kh;
                    if (r >= 0 && r < 4)
                        acc[r] = __builtin_amdgcn_mfma_f32_32x32x16_f16(A[cur][kh * 3 + kw], Bf[iy], acc[r], 0, 0, 0);
                }
            }
        }
        asm volatile("s_waitcnt lgkmcnt(0)" ::: "memory");
        __builtin_amdgcn_sched_barrier(0);
        __builtin_amdgcn_s_barrier();
        __builtin_amdgcn_sched_barrier(0);
    }
    #undef STAGEQ

    const float* bb = bias + b * 64;
    #pragma unroll
    for (int r = 0; r < 4; ++r) {
        const int yo = Y0g + Lb + r;
        float* ob = out + (((size_t)(b * 64 + ot * 32)) * 128 + yo) * 128 + X0 + px;
        #pragma unroll
        for (int reg = 0; reg < 16; ++reg) {
            const int ocl = (reg & 3) + 8 * (reg >> 2) + 4 * jj;
            ob[(size_t)ocl * 16384] = acc[r][reg] + bb[ot * 32 + ocl];
        }
    }
}

// ===================== FALLBACK (fp32 direct, R1) =====================
__global__ __launch_bounds__(256) void cond_gemm(const float* __restrict__ cond,
                                                 const float* __restrict__ Wc,
                                                 const float* __restrict__ bc,
                                                 float* __restrict__ wb) {
    __shared__ float condl[B_][CONDC + 1];
    __shared__ float Wl[16][CONDC + 1];
    const int tid = threadIdx.x;
    const int p0 = blockIdx.x * 16;
    for (int i = tid; i < B_ * CONDC; i += 256) condl[i >> 8][i & 255] = cond[i];
    for (int i = tid; i < 16 * CONDC; i += 256) {
        int pl = i >> 8, k = i & 255;
        Wl[pl][k] = Wc[(p0 + pl) * CONDC + k];
    }
    __syncthreads();
    const int pl = tid >> 4;
    const int b  = tid & 15;
    float acc = bc[p0 + pl];
    #pragma unroll 8
    for (int k = 0; k < CONDC; ++k) acc += Wl[pl][k] * condl[b][k];
    wb[b * NPARAM + p0 + pl] = tanhf(acc) * 5.0f;
}

#define TS  32
#define OG  8
#define ICC 8
__global__ __launch_bounds__(256) void conv_kernel(const float* __restrict__ x,
                                                   const float* __restrict__ wb,
                                                   float* __restrict__ out) {
    __shared__ float fxs[ICC][TS + 2][TS + 2];
    __shared__ float ws[OG][ICC][9];
    const int tid = threadIdx.x;
    const int b   = blockIdx.z;
    const int ocg = blockIdx.y * OG;
    const int tx0 = (blockIdx.x & 3) * TS;
    const int ty0 = (blockIdx.x >> 2) * TS;
    const int px  = (tid & 15) * 2;
    const int py  = (tid >> 4) * 2;
    float acc[OG][4];
    #pragma unroll
    for (int o = 0; o < OG; ++o)
        #pragma unroll
        for (int q = 0; q < 4; ++q) acc[o][q] = 0.0f;
    const float* wbase = wb + b * NPARAM;
    for (int ic0 = 0; ic0 < ICn; ic0 += ICC) {
        for (int i = tid; i < ICC * (TS + 2) * (TS + 2); i += 256) {
            int icl = i / ((TS + 2) * (TS + 2));
            int rem = i % ((TS + 2) * (TS + 2));
            int yy = rem / (TS + 2), xx = rem % (TS + 2);
            int gy = ty0 - 1 + yy, gx = tx0 - 1 + xx;
            float v = 0.0f;
            if (gy >= 0 && gy < Hn && gx >= 0 && gx < Wn)
                v = x[((b * ICn + ic0 + icl) * Hn + gy) * Wn + gx];
            fxs[icl][yy][xx] = v;
        }
        for (int i = tid; i < OG * ICC * 9; i += 256) {
            int o = i / (ICC * 9), rem = i % (ICC * 9);
            int icl = rem / 9, k = rem % 9;
            ws[o][icl][k] = wbase[((ocg + o) * ICn + ic0 + icl) * 9 + k];
        }
        __syncthreads();
        #pragma unroll
        for (int icl = 0; icl < ICC; ++icl) {
            float xv[4][4];
            #pragma unroll
            for (int dy = 0; dy < 4; ++dy)
                #pragma unroll
                for (int dx = 0; dx < 4; ++dx) xv[dy][dx] = fxs[icl][py + dy][px + dx];
            #pragma unroll
            for (int o = 0; o < OG; ++o)
                #pragma unroll
                for (int kh = 0; kh < 3; ++kh)
                    #pragma unroll
                    for (int kw = 0; kw < 3; ++kw) {
                        float wv = ws[o][icl][kh * 3 + kw];
                        acc[o][0] += xv[kh][kw] * wv;
                        acc[o][1] += xv[kh][kw + 1] * wv;
                        acc[o][2] += xv[kh + 1][kw] * wv;
                        acc[o][3] += xv[kh + 1][kw + 1] * wv;
                    }
        }
        __syncthreads();
    }
    #pragma unroll
    for (int o = 0; o < OG; ++o) {
        float bias = wbase[NW + ocg + o];
        int oc = ocg + o;
        float* obase = out + ((size_t)(b * OCn + oc) * Hn + (ty0 + py)) * Wn + tx0 + px;
        obase[0] = acc[o][0] + bias;
        obase[1] = acc[o][1] + bias;
        obase[Wn] = acc[o][2] + bias;
        obase[Wn + 1] = acc[o][3] + bias;
    }
}

// ===================== LAUNCH =====================
extern "C" void kernel_launch(void* const* d_in, const int* in_sizes, int n_in,
                              void* d_out, int out_size, void* d_ws, size_t ws_size,
                              hipStream_t stream) {
    const float* x    = (const float*)d_in[0];
    const float* cond = (const float*)d_in[1];
    const float* Wc   = (const float*)d_in[2];
    const float* bc   = (const float*)d_in[3];
    float* out = (float*)d_out;

    const size_t WT_BYTES = (size_t)B_ * 9 * 64 * 64 * 2;            // 1179648
    const size_t BIAS_OFF = WT_BYTES;
    const size_t XT_OFF   = 1183744;                                  // 256-aligned
    const size_t XT_BYTES = (size_t)B_ * 130 * 130 * 64 * 2 + 32768;  // + stage-overread pad
    const size_t NEED     = XT_OFF + XT_BYTES;

    if (ws_size >= NEED) {
        _Float16* wt   = (_Float16*)d_ws;
        float*    bias = (float*)((char*)d_ws + BIAS_OFF);
        _Float16* xt   = (_Float16*)((char*)d_ws + XT_OFF);
        prep<<<dim3(2048 + 32 + 1154), 256, 0, stream>>>(x, cond, Wc, bc, xt, wt, bias);
        conv_v4<<<dim3(4, 8, 16), 512, 0, stream>>>(xt, wt, bias, out);
    } else {
        float* wbuf = (float*)d_ws;
        cond_gemm<<<dim3(NPARAM / 16), 256, 0, stream>>>(cond, Wc, bc, wbuf);
        conv_kernel<<<dim3(16, OCn / OG, B_), 256, 0, stream>>>(x, wbuf, out);
    }
}